// Round 7
// baseline (1374.766 us; speedup 1.0000x reference)
//
#include <hip/hip_runtime.h>

#define BN_EPS 1e-5f

typedef __attribute__((ext_vector_type(8))) short bf16x8;
typedef __attribute__((ext_vector_type(4))) float f32x4;

// ---------------- CSR build: histogram of dst ----------------
__global__ void k_hist(const int* __restrict__ dst, int* __restrict__ deg, int E) {
    int e = blockIdx.x * blockDim.x + threadIdx.x;
    if (e < E) atomicAdd(&deg[dst[e]], 1);
}

// ---------------- scan phase 1: per-block sums (1024 elems / 256-thread block) --
__global__ __launch_bounds__(256) void k_blocksum(const int* __restrict__ deg,
                                                  int* __restrict__ bsum, int N) {
    __shared__ int red[256];
    int tid = threadIdx.x;
    int base = blockIdx.x * 1024 + tid * 4;
    int s = 0;
    if (base + 3 < N) {
        int4 v = *(const int4*)&deg[base];
        s = v.x + v.y + v.z + v.w;
    } else {
        for (int i = 0; i < 4; ++i) if (base + i < N) s += deg[base + i];
    }
    red[tid] = s;
    __syncthreads();
    for (int d = 128; d > 0; d >>= 1) {
        if (tid < d) red[tid] += red[tid + d];
        __syncthreads();
    }
    if (tid == 0) bsum[blockIdx.x] = red[0];
}

// ---------------- scan phase 2: exclusive scan of block sums (nb <= 1024) -------
__global__ __launch_bounds__(1024) void k_scanpartials(int* __restrict__ bsum, int nb) {
    __shared__ int t[1024];
    int tid = threadIdx.x;
    int v = (tid < nb) ? bsum[tid] : 0;
    t[tid] = v;
    __syncthreads();
    for (int d = 1; d < 1024; d <<= 1) {
        int u = (tid >= d) ? t[tid - d] : 0;
        __syncthreads();
        t[tid] += u;
        __syncthreads();
    }
    if (tid < nb) bsum[tid] = t[tid] - v;  // exclusive
}

// ---- scan phase 3: per-block scan + offset, write rowptr (+ bucket cursors) ----
// Buckets are 128 dst nodes now (gcur at 128-node boundaries).
__global__ __launch_bounds__(256) void k_applyscan(const int* __restrict__ deg,
                                                   const int* __restrict__ bsum,
                                                   int* __restrict__ rowptr,
                                                   int* __restrict__ gcur, int N, int E) {
    __shared__ int red[256];
    int tid = threadIdx.x;
    int base = blockIdx.x * 1024 + tid * 4;
    int v0 = 0, v1 = 0, v2 = 0, v3 = 0;
    if (base + 3 < N) {
        int4 v = *(const int4*)&deg[base];
        v0 = v.x; v1 = v.y; v2 = v.z; v3 = v.w;
    } else {
        if (base < N) v0 = deg[base];
        if (base + 1 < N) v1 = deg[base + 1];
        if (base + 2 < N) v2 = deg[base + 2];
        if (base + 3 < N) v3 = deg[base + 3];
    }
    int s = v0 + v1 + v2 + v3;
    red[tid] = s;
    __syncthreads();
    for (int d = 1; d < 256; d <<= 1) {
        int u = (tid >= d) ? red[tid - d] : 0;
        __syncthreads();
        red[tid] += u;
        __syncthreads();
    }
    int off = bsum[blockIdx.x] + red[tid] - s;
    int r0 = off, r1 = off + v0, r2 = r1 + v1, r3 = r2 + v2;
    if (base < N)     rowptr[base] = r0;
    if (base + 1 < N) rowptr[base + 1] = r1;
    if (base + 2 < N) rowptr[base + 2] = r2;
    if (base + 3 < N) rowptr[base + 3] = r3;
    if ((base & 127) == 0 && base < N) gcur[base >> 7] = r0;  // 128-node buckets
    if (blockIdx.x == 0 && tid == 0) rowptr[N] = E;
}

// ------- sort pass A: partition edges into 128-node dst buckets (N <= 131072) ---
// Payload: [attr:32 | dst&127:8 | src:24]
#define ABLK 8192
__global__ __launch_bounds__(1024) void k_binA(const int* __restrict__ src,
                                               const int* __restrict__ dst,
                                               const float* __restrict__ attr,
                                               int* __restrict__ gcur,
                                               unsigned long long* __restrict__ tmp,
                                               int E, int N) {
    __shared__ int hist[1024];
    __shared__ int lcur[1024];
    int tid = threadIdx.x;
    int NB = (N + 127) >> 7;  // <= 1024 for N <= 131072
    int e0 = blockIdx.x * ABLK;
    int e1 = e0 + ABLK; if (e1 > E) e1 = E;
    for (int i = tid; i < NB; i += 1024) hist[i] = 0;
    __syncthreads();
    for (int e = e0 + tid; e < e1; e += 1024) atomicAdd(&hist[dst[e] >> 7], 1);
    __syncthreads();
    for (int b = tid; b < NB; b += 1024) {
        int hc = hist[b];
        lcur[b] = hc ? atomicAdd(&gcur[b], hc) : 0;
    }
    __syncthreads();
    for (int e = e0 + tid; e < e1; e += 1024) {
        int d = dst[e];
        int pos = atomicAdd(&lcur[d >> 7], 1);
        unsigned long long p = ((unsigned long long)__float_as_uint(attr[e]) << 32) |
                               ((unsigned long long)(d & 127) << 24) |
                               (unsigned int)src[e];
        tmp[pos] = p;
    }
}

// ------- sort pass B2: per 128-dst bucket, order edges by src>>8 (coarse) -------
// so each gather workgroup sweeps src-space in ascending order (L2-window).
__global__ __launch_bounds__(512) void k_binB2(const int* __restrict__ rowptr,
                                               const unsigned long long* __restrict__ tmp,
                                               unsigned long long* __restrict__ edata,
                                               int N) {
    __shared__ int hist[512];
    __shared__ int scn[512];
    __shared__ int cur[512];
    int b = blockIdx.x;
    int tid = threadIdx.x;
    int nb0 = b << 7;
    int beg = rowptr[nb0];
    int endnode = nb0 + 128; if (endnode > N) endnode = N;
    int end = rowptr[endnode];
    hist[tid] = 0;
    __syncthreads();
    for (int e = beg + tid; e < end; e += 512)
        atomicAdd(&hist[((unsigned)tmp[e] & 0xFFFFFFu) >> 8], 1);
    __syncthreads();
    int v = hist[tid];
    scn[tid] = v;
    __syncthreads();
    for (int d = 1; d < 512; d <<= 1) {
        int u = (tid >= d) ? scn[tid - d] : 0;
        __syncthreads();
        scn[tid] += u;
        __syncthreads();
    }
    cur[tid] = beg + scn[tid] - v;  // exclusive
    __syncthreads();
    for (int e = beg + tid; e < end; e += 512) {
        unsigned long long p = tmp[e];
        int sb = ((unsigned)p & 0xFFFFFFu) >> 8;
        int pos = atomicAdd(&cur[sb], 1);
        edata[pos] = p;
    }
}

// ---- inline BN scale/shift from raw stats ----
__device__ __forceinline__ void bn_coeff(const float* bs, const float* gam,
                                         const float* bet, int c, float inv_n,
                                         float& sc, float& sh) {
    float mean = bs[c] * inv_n;
    float var = bs[64 + c] * inv_n - mean * mean;
    sc = gam[c] * rsqrtf(fmaxf(var, 0.f) + BN_EPS);
    sh = bet[c] - mean * sc;
}

__device__ __forceinline__ float h16lo(unsigned u) {
    return (float)__builtin_bit_cast(_Float16, (unsigned short)(u & 0xFFFFu));
}
__device__ __forceinline__ float h16hi(unsigned u) {
    return (float)__builtin_bit_cast(_Float16, (unsigned short)(u >> 16));
}

// ---- layer-0 bucket gather on raw x (N x 4) with LDS accumulators.
// One block per 128-dst bucket; 4 lanes per edge (one per channel); degw too. --
__global__ __launch_bounds__(256) void k_gather4S(const int* __restrict__ rowptr,
                                                  const unsigned long long* __restrict__ edata,
                                                  const float* __restrict__ x,
                                                  float* __restrict__ g4,
                                                  float* __restrict__ degw, int N) {
    __shared__ float acc4[512];   // 128 nodes x 4 ch
    __shared__ float dwacc[128];
    int b = blockIdx.x;
    int tid = threadIdx.x;
    int nb0 = b << 7;
    int beg = rowptr[nb0];
    int endnode = nb0 + 128; if (endnode > N) endnode = N;
    int end = rowptr[endnode];
    for (int i = tid; i < 512; i += 256) acc4[i] = 0.f;
    if (tid < 128) dwacc[tid] = 0.f;
    __syncthreads();
    int lane = tid & 63;
    int w = tid >> 6;       // wave 0..3
    int el = lane >> 2;     // edge slot 0..15
    int ch = lane & 3;
    for (int base = beg + w * 32; base < end; base += 128) {
#pragma unroll
        for (int j = 0; j < 2; ++j) {
            int e = base + j * 16 + el;
            unsigned long long p = (e < end) ? edata[e] : 0ull;  // p=0 -> w=0
            float wt = __uint_as_float((unsigned)(p >> 32));
            unsigned srcb = ((unsigned)p & 0xFFFFFFu);
            float v = *(const float*)((const char*)x + (srcb << 4) + (ch << 2));
            int dl = (int)((p >> 24) & 127u);
            atomicAdd(&acc4[dl * 4 + ch], wt * v);
            if (ch == 0) atomicAdd(&dwacc[dl], wt);
        }
    }
    __syncthreads();
    if (tid < 128) {
        int n = nb0 + tid;
        if (n < N) {
            *(float4*)&g4[(size_t)n * 4] = *(float4*)&acc4[tid * 4];
            degw[n] = dwacc[tid];
        }
    }
}

// ---- activation materialization: a16 = fp16(relu(BN(h))), linear [N][64] ----
__global__ __launch_bounds__(256) void k_act(const float* __restrict__ h,
                                             const float* __restrict__ bs,
                                             const float* __restrict__ gam,
                                             const float* __restrict__ bet,
                                             unsigned short* __restrict__ a16,
                                             int N) {
    __shared__ float scS[64], shS[64];
    int tid = threadIdx.x;
    if (tid < 64) {
        float sc, sh;
        bn_coeff(bs, gam, bet, tid, 1.f / (float)N, sc, sh);
        scS[tid] = sc; shS[tid] = sh;
    }
    __syncthreads();
    int c0 = (tid & 15) << 2;
    float4 scv = *(const float4*)&scS[c0];
    float4 shv = *(const float4*)&shS[c0];
    int total = N << 4;  // N*64/4 chunks
    for (int t = blockIdx.x * 256 + tid; t < total; t += gridDim.x * 256) {
        float4 v = *(const float4*)&h[(size_t)t * 4];
        float r0 = fmaxf(fmaf(v.x, scv.x, shv.x), 0.f);
        float r1 = fmaxf(fmaf(v.y, scv.y, shv.y), 0.f);
        float r2 = fmaxf(fmaf(v.z, scv.z, shv.z), 0.f);
        float r3 = fmaxf(fmaf(v.w, scv.w, shv.w), 0.f);
        unsigned q0 = __builtin_bit_cast(unsigned short, (_Float16)r0);
        unsigned q1 = __builtin_bit_cast(unsigned short, (_Float16)r1);
        unsigned q2 = __builtin_bit_cast(unsigned short, (_Float16)r2);
        unsigned q3 = __builtin_bit_cast(unsigned short, (_Float16)r3);
        uint2 o; o.x = q0 | (q1 << 16); o.y = q2 | (q3 << 16);
        *(uint2*)&a16[(size_t)t * 4] = o;
    }
}

// ------- src-swept bucket gather: one block per 128-dst bucket, 32KB LDS accum.
// Segment is sorted by src>>8 (binB2); all 782 blocks co-resident sweep src
// space in lockstep -> a16 reads hit a small L2-resident window. Each half-wave
// processes 4 edges/iter, reading the FULL 128B row (32 lanes x 4B = 2 fp16
// channels each) and accumulating via LDS atomicAdd (2-way bank alias = free).
__global__ __launch_bounds__(512) void k_gatherS(const int* __restrict__ rowptr,
                                                 const unsigned long long* __restrict__ edata,
                                                 const unsigned short* __restrict__ a16,
                                                 float* __restrict__ S, int N) {
    __shared__ float acc[8192];  // 128 nodes x 64 ch
    int b = blockIdx.x;
    int tid = threadIdx.x;
    int nb0 = b << 7;
    int beg = rowptr[nb0];
    int endnode = nb0 + 128; if (endnode > N) endnode = N;
    int end = rowptr[endnode];
    {
        float4 z = {0.f, 0.f, 0.f, 0.f};
        for (int i = tid; i < 2048; i += 512) *(float4*)&acc[i * 4] = z;
    }
    __syncthreads();
    int lane = tid & 63;
    int u = ((tid >> 6) << 1) | ((lane >> 5) & 1);  // half-wave unit 0..15
    int cp = lane & 31;                              // channel pair 0..31
    for (int base = beg + u * 4; base < end; base += 64) {
        unsigned long long p0 = edata[base];
        unsigned long long p1 = (base + 1 < end) ? edata[base + 1] : 0ull;
        unsigned long long p2 = (base + 2 < end) ? edata[base + 2] : 0ull;
        unsigned long long p3 = (base + 3 < end) ? edata[base + 3] : 0ull;
#pragma unroll
        for (int j = 0; j < 4; ++j) {
            unsigned long long p = (j == 0) ? p0 : (j == 1) ? p1 : (j == 2) ? p2 : p3;
            float wt = __uint_as_float((unsigned)(p >> 32));   // p=0 -> wt=0
            unsigned off = (((unsigned)p & 0xFFFFFFu) << 7) | (cp << 2);
            unsigned v = *(const unsigned*)((const char*)a16 + off);
            int dl = (int)((p >> 24) & 127u);
            atomicAdd(&acc[dl * 64 + (cp << 1)], wt * h16lo(v));
            atomicAdd(&acc[dl * 64 + (cp << 1) + 1], wt * h16hi(v));
        }
    }
    __syncthreads();
    for (int i = tid; i < 2048; i += 512) {
        int idx = i * 4;
        int n = nb0 + (idx >> 6);
        if (n < N) *(float4*)&S[(size_t)n * 64 + (idx & 63)] = *(float4*)&acc[idx];
    }
}

// ---- bf16x3 split helpers ----
__device__ __forceinline__ void split_pack8(const float* v, uint4& H, uint4& L) {
    unsigned hb[8], lb[8];
#pragma unroll
    for (int j = 0; j < 8; ++j) {
        unsigned b = __float_as_uint(v[j]);
        unsigned rb = (b + 0x7FFFu + ((b >> 16) & 1u)) & 0xFFFF0000u;  // RNE bf16
        hb[j] = rb >> 16;
        float lo = v[j] - __uint_as_float(rb);  // exact
        lb[j] = __float_as_uint(lo) >> 16;
    }
    H.x = hb[0] | (hb[1] << 16); H.y = hb[2] | (hb[3] << 16);
    H.z = hb[4] | (hb[5] << 16); H.w = hb[6] | (hb[7] << 16);
    L.x = lb[0] | (lb[1] << 16); L.y = lb[2] | (lb[3] << 16);
    L.z = lb[4] | (lb[5] << 16); L.w = lb[6] | (lb[7] << 16);
}

__device__ __forceinline__ void split_frag(const float* w, bf16x8& hi, bf16x8& lo) {
#pragma unroll
    for (int j = 0; j < 8; ++j) {
        unsigned b = __float_as_uint(w[j]);
        unsigned rb = (b + 0x7FFFu + ((b >> 16) & 1u)) & 0xFFFF0000u;
        hi[j] = (short)(rb >> 16);
        float lof = w[j] - __uint_as_float(rb);
        lo[j] = (short)(__float_as_uint(lof) >> 16);
    }
}

// --- h_raw_out = S@W1 + x@W3 - dw*(x@W2) + dw*b1 + b3 via bf16x3 MFMA.
// PRE=1: x_i operand read from linear fp16 a16 (exact hi/lo split). EMB=1:
// layer 0, S/x rows reconstructed from g4/x via Wemb during staging.
template <int PRE, int EMB>
__global__ __launch_bounds__(512) void k_update(
    const float* __restrict__ S, float* __restrict__ h,
    const float* __restrict__ degw,
    const float* __restrict__ xin, const float* __restrict__ g4,
    const float* __restrict__ Wemb, const float* __restrict__ bemb,
    const unsigned short* __restrict__ a16,
    const float* __restrict__ W1, const float* __restrict__ b1,
    const float* __restrict__ W2, const float* __restrict__ W3,
    const float* __restrict__ b3,
    float* __restrict__ bnstats, int N) {
    // [Shi | Slo | Hhi | Hlo], 4096 ushorts (8KB) each = 32KB
    __shared__ __align__(16) unsigned short sA[16384];
    __shared__ float dwS[64];

    int tid = threadIdx.x;
    int lane = tid & 63;
    int wv = tid >> 6;            // wave 0..7
    int mg = wv >> 2;             // row-group: rows mg*32 .. mg*32+31
    int nb = wv & 3;              // col-block: cols nb*16 .. nb*16+15
    int c = (nb << 4) | (lane & 15);
    int krow = (lane >> 4) << 3;  // k-offset of this lane's fragment elems

    // ---- B fragments (weights) in registers, one-time ----
    bf16x8 B1h[2], B1l[2], B2h[2], B2l[2], B3h[2], B3l[2];
#pragma unroll
    for (int ks = 0; ks < 2; ++ks) {
        float w1v[8], w2v[8], w3v[8];
        int kb = ks * 32 + krow;
#pragma unroll
        for (int j = 0; j < 8; ++j) {
            int idx = (kb + j) * 64 + c;
            w1v[j] = W1[idx];
            w2v[j] = W2[idx];
            w3v[j] = W3[idx];
        }
        split_frag(w1v, B1h[ks], B1l[ks]);
        split_frag(w2v, B2h[ks], B2l[ks]);
        split_frag(w3v, B3h[ks], B3l[ks]);
    }
    float b1c = b1[c], b3c = b3[c];

    // ---- staging role: thread handles row r, k-chunk kg (8 consecutive k) ----
    int r = tid >> 3;   // 0..63
    int kg = tid & 7;   // 0..7
    int k0 = kg << 3;
    int slot = ((((r >> 4) * 2 + (kg >> 2)) * 64) + ((kg & 3) << 4) + (r & 15)) * 8;

    float we0[8], we1[8], we2[8], we3[8], bev[8];
    if (EMB) {
#pragma unroll
        for (int j = 0; j < 8; ++j) {
            we0[j] = Wemb[k0 + j];
            we1[j] = Wemb[64 + k0 + j];
            we2[j] = Wemb[128 + k0 + j];
            we3[j] = Wemb[192 + k0 + j];
            bev[j] = bemb[k0 + j];
        }
    }

    float bsum = 0.f, bsq = 0.f;
    int numTiles = (N + 63) >> 6;
    for (int tile = blockIdx.x; tile < numTiles; tile += gridDim.x) {
        int n0 = tile << 6;
        __syncthreads();  // protect LDS from previous iteration's readers
        {
            int n = n0 + r;
            float sv[8], hv[8];
            if (n < N) {
                if (EMB) {
                    float4 g = *(const float4*)&g4[(size_t)n * 4];
                    float4 xr = *(const float4*)&xin[(size_t)n * 4];
                    float dw = degw[n];
#pragma unroll
                    for (int j = 0; j < 8; ++j) {
                        sv[j] = fmaf(g.x, we0[j], fmaf(g.y, we1[j],
                                 fmaf(g.z, we2[j], fmaf(g.w, we3[j], dw * bev[j]))));
                        hv[j] = fmaf(xr.x, we0[j], fmaf(xr.y, we1[j],
                                 fmaf(xr.z, we2[j], fmaf(xr.w, we3[j], bev[j]))));
                    }
                } else {
                    const float* Sp = &S[(size_t)n * 64 + k0];
                    float4 s0_ = *(const float4*)Sp;
                    float4 s1_ = *(const float4*)(Sp + 4);
                    sv[0]=s0_.x; sv[1]=s0_.y; sv[2]=s0_.z; sv[3]=s0_.w;
                    sv[4]=s1_.x; sv[5]=s1_.y; sv[6]=s1_.z; sv[7]=s1_.w;
                    uint4 hp = *(const uint4*)((const char*)a16 + (((size_t)n) << 7) + (k0 << 1));
                    hv[0] = h16lo(hp.x); hv[1] = h16hi(hp.x);
                    hv[2] = h16lo(hp.y); hv[3] = h16hi(hp.y);
                    hv[4] = h16lo(hp.z); hv[5] = h16hi(hp.z);
                    hv[6] = h16lo(hp.w); hv[7] = h16hi(hp.w);
                }
            } else {
#pragma unroll
                for (int j = 0; j < 8; ++j) { sv[j] = 0.f; hv[j] = 0.f; }
            }
            uint4 H, L;
            split_pack8(sv, H, L);
            *(uint4*)&sA[slot] = H;
            *(uint4*)&sA[4096 + slot] = L;
            split_pack8(hv, H, L);
            *(uint4*)&sA[8192 + slot] = H;
            *(uint4*)&sA[12288 + slot] = L;
            if (tid < 64) dwS[tid] = (n0 + tid < N) ? degw[n0 + tid] : 0.f;
        }
        __syncthreads();
        // ---- MFMA: acc over K=64 (2 K-steps), 2 M-subtiles per wave ----
        f32x4 accP[2] = {{0.f,0.f,0.f,0.f},{0.f,0.f,0.f,0.f}};
        f32x4 accN[2] = {{0.f,0.f,0.f,0.f},{0.f,0.f,0.f,0.f}};
#pragma unroll
        for (int ks = 0; ks < 2; ++ks) {
#pragma unroll
            for (int mtg = 0; mtg < 2; ++mtg) {
                int mt = mg * 2 + mtg;
                int base = ((mt * 2 + ks) * 64 + lane) * 8;
                bf16x8 aSh = *(const bf16x8*)&sA[base];
                bf16x8 aSl = *(const bf16x8*)&sA[4096 + base];
                bf16x8 aHh = *(const bf16x8*)&sA[8192 + base];
                bf16x8 aHl = *(const bf16x8*)&sA[12288 + base];
                f32x4 p = accP[mtg], q = accN[mtg];
                p = __builtin_amdgcn_mfma_f32_16x16x32_bf16(aSh, B1h[ks], p, 0, 0, 0);
                p = __builtin_amdgcn_mfma_f32_16x16x32_bf16(aSl, B1h[ks], p, 0, 0, 0);
                p = __builtin_amdgcn_mfma_f32_16x16x32_bf16(aSh, B1l[ks], p, 0, 0, 0);
                p = __builtin_amdgcn_mfma_f32_16x16x32_bf16(aHh, B3h[ks], p, 0, 0, 0);
                p = __builtin_amdgcn_mfma_f32_16x16x32_bf16(aHl, B3h[ks], p, 0, 0, 0);
                p = __builtin_amdgcn_mfma_f32_16x16x32_bf16(aHh, B3l[ks], p, 0, 0, 0);
                q = __builtin_amdgcn_mfma_f32_16x16x32_bf16(aHh, B2h[ks], q, 0, 0, 0);
                q = __builtin_amdgcn_mfma_f32_16x16x32_bf16(aHl, B2h[ks], q, 0, 0, 0);
                q = __builtin_amdgcn_mfma_f32_16x16x32_bf16(aHh, B2l[ks], q, 0, 0, 0);
                accP[mtg] = p; accN[mtg] = q;
            }
        }
        // ---- epilogue: C layout col=lane&15, row=(lane>>4)*4+j ----
#pragma unroll
        for (int mtg = 0; mtg < 2; ++mtg) {
            int rowb = mg * 32 + mtg * 16 + ((lane >> 4) << 2);
            float4 dwv = *(const float4*)&dwS[rowb];
            float dwa[4] = {dwv.x, dwv.y, dwv.z, dwv.w};
#pragma unroll
            for (int j = 0; j < 4; ++j) {
                int n = n0 + rowb + j;
                if (n < N) {
                    float val = accP[mtg][j] - dwa[j] * accN[mtg][j] + dwa[j] * b1c + b3c;
                    h[(size_t)n * 64 + c] = val;  // raw (pre-BN)
                    bsum += val;
                    bsq += val * val;
                }
            }
        }
    }
    // ---- BN stats reduction (reuse sA as 1024 floats) ----
    __syncthreads();
    float* red = (float*)sA;
    red[tid] = bsum;
    red[512 + tid] = bsq;
    __syncthreads();
    if (tid < 64) {
        int nb_ = tid >> 4, cl = tid & 15;
        float s = 0.f, qq = 0.f;
#pragma unroll
        for (int i = 0; i < 8; ++i) {
            int t = ((i & 1) << 8) + (nb_ << 6) + ((i >> 1) << 4) + cl;
            s += red[t];
            qq += red[512 + t];
        }
        atomicAdd(&bnstats[tid], s);
        atomicAdd(&bnstats[64 + tid], qq);
    }
}

// ------- pool phase 1: per-graph sums of act(h_raw), sorted-run + atomics -------
#define POOL_TILE 128
__global__ __launch_bounds__(256) void k_poolsum(const float* __restrict__ h,
                                                 const int* __restrict__ batch,
                                                 const float* __restrict__ bsp,
                                                 const float* __restrict__ gamp,
                                                 const float* __restrict__ betp,
                                                 float* __restrict__ gsums, int N) {
    int tid = threadIdx.x;
    int c = tid & 63, q = tid >> 6;
    float sc, sh_;
    bn_coeff(bsp, gamp, betp, c, 1.f / (float)N, sc, sh_);
    int n0 = blockIdx.x * POOL_TILE;
    int nEnd = n0 + POOL_TILE; if (nEnd > N) nEnd = N;
    int g = -1;
    float acc = 0.f;
    for (int n = n0 + q; n < nEnd; n += 4) {
        int b = batch[n];
        if (b != g) {
            if (g >= 0) atomicAdd(&gsums[(size_t)g * 64 + c], acc);
            g = b; acc = 0.f;
        }
        acc += fmaxf(fmaf(h[(size_t)n * 64 + c], sc, sh_), 0.f);
    }
    if (g >= 0) atomicAdd(&gsums[(size_t)g * 64 + c], acc);
}

// ------- pool phase 2: divide by count + MLP head (one 64-thread block / graph) -
__global__ void k_head(const float* __restrict__ gsums, const int* __restrict__ batch,
                       const float* __restrict__ Wl1, const float* __restrict__ bl1,
                       const float* __restrict__ Wl2, const float* __restrict__ bl2,
                       float* __restrict__ out, int N) {
    int g = blockIdx.x;
    int c = threadIdx.x;  // 64 threads
    int lo = 0, hi = N;
    while (lo < hi) { int mid = (lo + hi) >> 1; if (batch[mid] < g) lo = mid + 1; else hi = mid; }
    int start = lo;
    hi = N;
    while (lo < hi) { int mid = (lo + hi) >> 1; if (batch[mid] < g + 1) lo = mid + 1; else hi = mid; }
    int cnt = lo - start;
    float denom = (float)(cnt > 0 ? cnt : 1);
    __shared__ float gS[64], yS[64];
    gS[c] = gsums[(size_t)g * 64 + c] / denom;
    __syncthreads();
    float y = bl1[c];
    for (int k = 0; k < 64; ++k) y += gS[k] * Wl1[k * 64 + c];
    yS[c] = fmaxf(y, 0.f);
    __syncthreads();
    if (c < 3) {
        float o = bl2[c];
        for (int k = 0; k < 64; ++k) o += yS[k] * Wl2[k * 3 + c];
        out[g * 3 + c] = o;
    }
}

extern "C" void kernel_launch(void* const* d_in, const int* in_sizes, int n_in,
                              void* d_out, int out_size, void* d_ws, size_t ws_size,
                              hipStream_t stream) {
    const float* x     = (const float*)d_in[0];
    const int*   eid   = (const int*)d_in[1];
    const float* attr  = (const float*)d_in[2];
    const int*   batch = (const int*)d_in[3];
    const float* Wemb  = (const float*)d_in[4];
    const float* bemb  = (const float*)d_in[5];
    const float* W1    = (const float*)d_in[6];
    const float* b1    = (const float*)d_in[7];
    const float* W2    = (const float*)d_in[8];
    const float* W3    = (const float*)d_in[9];
    const float* b3    = (const float*)d_in[10];
    const float* gamma = (const float*)d_in[11];
    const float* beta  = (const float*)d_in[12];
    const float* Wl1   = (const float*)d_in[13];
    const float* bl1   = (const float*)d_in[14];
    const float* Wl2   = (const float*)d_in[15];
    const float* bl2   = (const float*)d_in[16];

    int N = in_sizes[3];
    int E = in_sizes[2];
    int L = in_sizes[7] / 64;
    int G = out_size / 3;

    const int* src = eid;
    const int* dst = eid + E;

    float* ws      = (float*)d_ws;
    float* h       = ws;                       // N*64
    float* S       = h + (size_t)N * 64;       // N*64
    float* degw    = S + (size_t)N * 64;       // N
    float* g4      = degw + N;                 // N*4
    float* bnstats = g4 + (size_t)N * 4;       // 3*128 (per-layer slots)
    float* gsums   = bnstats + 3 * 128;        // G*64
    int*   deg     = (int*)(gsums + (size_t)G * 64);  // N
    int*   rowptr  = deg + N;                  // N+2
    int*   bsum    = rowptr + (N + 2);         // 1024
    int*   gcur    = bsum + 1024;              // 1024 (bucket cursors)
    unsigned long long* edata = (unsigned long long*)(gcur + 1024);  // E
    unsigned long long* tmp   = edata + E;                           // E
    unsigned short* a16 = (unsigned short*)(((uintptr_t)(tmp + E) + 15) & ~(uintptr_t)15);  // N*64 fp16 linear

    int nScanBlocks = (N + 1023) / 1024;
    int NB = (N + 127) >> 7;  // 128-node buckets (requires N <= 131072)

    // ---- CSR build + two-level sort: dst-bucket-major, src-coarse-minor ----
    hipMemsetAsync(deg, 0, (size_t)N * sizeof(int), stream);
    hipMemsetAsync(bnstats, 0, 3 * 128 * sizeof(float), stream);
    k_hist<<<(E + 255) / 256, 256, 0, stream>>>(dst, deg, E);
    k_blocksum<<<nScanBlocks, 256, 0, stream>>>(deg, bsum, N);
    k_scanpartials<<<1, 1024, 0, stream>>>(bsum, nScanBlocks);
    k_applyscan<<<nScanBlocks, 256, 0, stream>>>(deg, bsum, rowptr, gcur, N, E);
    k_binA<<<(E + ABLK - 1) / ABLK, 1024, 0, stream>>>(src, dst, attr, gcur, tmp, E, N);
    k_binB2<<<NB, 512, 0, stream>>>(rowptr, tmp, edata, N);

    // ---- layers ----
    for (int l = 0; l < L; ++l) {
        if (l == 0) {
            k_gather4S<<<NB, 256, 0, stream>>>(rowptr, edata, x, g4, degw, N);
            k_update<0, 1><<<512, 512, 0, stream>>>(S, h, degw, x, g4, Wemb, bemb,
                                                    nullptr,
                                                    W1, b1, W2, W3, b3, bnstats, N);
        } else {
            k_gatherS<<<NB, 512, 0, stream>>>(rowptr, edata, a16, S, N);
            k_update<1, 0><<<512, 512, 0, stream>>>(S, h, degw, nullptr, nullptr,
                                                    nullptr, nullptr, a16,
                                                    W1 + (size_t)l * 4096, b1 + (size_t)l * 64,
                                                    W2 + (size_t)l * 4096, W3 + (size_t)l * 4096,
                                                    b3 + (size_t)l * 64,
                                                    bnstats + (size_t)l * 128, N);
        }
        if (l + 1 < L) {
            k_act<<<1024, 256, 0, stream>>>(h, bnstats + (size_t)l * 128,
                                            gamma + (size_t)l * 64, beta + (size_t)l * 64,
                                            a16, N);
        }
    }

    // ---- pool (applies final BN affine + relu lazily) + head ----
    hipMemsetAsync(gsums, 0, (size_t)G * 64 * sizeof(float), stream);
    k_poolsum<<<(N + POOL_TILE - 1) / POOL_TILE, 256, 0, stream>>>(
        h, batch, bnstats + (size_t)(L - 1) * 128, gamma + (size_t)(L - 1) * 64,
        beta + (size_t)(L - 1) * 64, gsums, N);
    k_head<<<G, 64, 0, stream>>>(gsums, batch, Wl1, bl1, Wl2, bl2, (float*)d_out, N);
}

// Round 8
// 434.811 us; speedup vs baseline: 3.1618x; 3.1618x over previous
//
#include <hip/hip_runtime.h>

#define BN_EPS 1e-5f

typedef __attribute__((ext_vector_type(8))) short bf16x8;
typedef __attribute__((ext_vector_type(4))) float f32x4;

// ---------------- CSR build: histogram of dst ----------------
__global__ void k_hist(const int* __restrict__ dst, int* __restrict__ deg, int E) {
    int e = blockIdx.x * blockDim.x + threadIdx.x;
    if (e < E) atomicAdd(&deg[dst[e]], 1);
}

// ---------------- scan phase 1: per-block sums (1024 elems / 256-thread block) --
__global__ __launch_bounds__(256) void k_blocksum(const int* __restrict__ deg,
                                                  int* __restrict__ bsum, int N) {
    __shared__ int red[256];
    int tid = threadIdx.x;
    int base = blockIdx.x * 1024 + tid * 4;
    int s = 0;
    if (base + 3 < N) {
        int4 v = *(const int4*)&deg[base];
        s = v.x + v.y + v.z + v.w;
    } else {
        for (int i = 0; i < 4; ++i) if (base + i < N) s += deg[base + i];
    }
    red[tid] = s;
    __syncthreads();
    for (int d = 128; d > 0; d >>= 1) {
        if (tid < d) red[tid] += red[tid + d];
        __syncthreads();
    }
    if (tid == 0) bsum[blockIdx.x] = red[0];
}

// ---------------- scan phase 2: exclusive scan of block sums (nb <= 1024) -------
__global__ __launch_bounds__(1024) void k_scanpartials(int* __restrict__ bsum, int nb) {
    __shared__ int t[1024];
    int tid = threadIdx.x;
    int v = (tid < nb) ? bsum[tid] : 0;
    t[tid] = v;
    __syncthreads();
    for (int d = 1; d < 1024; d <<= 1) {
        int u = (tid >= d) ? t[tid - d] : 0;
        __syncthreads();
        t[tid] += u;
        __syncthreads();
    }
    if (tid < nb) bsum[tid] = t[tid] - v;  // exclusive
}

// ---- scan phase 3: per-block scan + offset, write rowptr (+ bucket cursors) ----
__global__ __launch_bounds__(256) void k_applyscan(const int* __restrict__ deg,
                                                   const int* __restrict__ bsum,
                                                   int* __restrict__ rowptr,
                                                   int* __restrict__ gcur, int N, int E) {
    __shared__ int red[256];
    int tid = threadIdx.x;
    int base = blockIdx.x * 1024 + tid * 4;
    int v0 = 0, v1 = 0, v2 = 0, v3 = 0;
    if (base + 3 < N) {
        int4 v = *(const int4*)&deg[base];
        v0 = v.x; v1 = v.y; v2 = v.z; v3 = v.w;
    } else {
        if (base < N) v0 = deg[base];
        if (base + 1 < N) v1 = deg[base + 1];
        if (base + 2 < N) v2 = deg[base + 2];
        if (base + 3 < N) v3 = deg[base + 3];
    }
    int s = v0 + v1 + v2 + v3;
    red[tid] = s;
    __syncthreads();
    for (int d = 1; d < 256; d <<= 1) {
        int u = (tid >= d) ? red[tid - d] : 0;
        __syncthreads();
        red[tid] += u;
        __syncthreads();
    }
    int off = bsum[blockIdx.x] + red[tid] - s;
    int r0 = off, r1 = off + v0, r2 = r1 + v1, r3 = r2 + v2;
    if (base < N)     rowptr[base] = r0;
    if (base + 1 < N) rowptr[base + 1] = r1;
    if (base + 2 < N) rowptr[base + 2] = r2;
    if (base + 3 < N) rowptr[base + 3] = r3;
    if ((base & 255) == 0 && base < N) gcur[base >> 8] = r0;  // fused k_initbcur
    if (blockIdx.x == 0 && tid == 0) rowptr[N] = E;
}

// ------- sort pass A: partition edges into 256-node buckets (requires N < 2^24) -
#define ABLK 8192
__global__ __launch_bounds__(1024) void k_binA(const int* __restrict__ src,
                                               const int* __restrict__ dst,
                                               const float* __restrict__ attr,
                                               int* __restrict__ gcur,
                                               unsigned long long* __restrict__ tmp,
                                               int E, int N) {
    __shared__ int hist[1024];
    __shared__ int lcur[1024];
    int tid = threadIdx.x;
    int NB = (N + 255) >> 8;  // <= 1024 for N <= 262144
    int e0 = blockIdx.x * ABLK;
    int e1 = e0 + ABLK; if (e1 > E) e1 = E;
    for (int i = tid; i < NB; i += 1024) hist[i] = 0;
    __syncthreads();
    for (int e = e0 + tid; e < e1; e += 1024) atomicAdd(&hist[dst[e] >> 8], 1);
    __syncthreads();
    for (int b = tid; b < NB; b += 1024) {
        int hc = hist[b];
        lcur[b] = hc ? atomicAdd(&gcur[b], hc) : 0;
    }
    __syncthreads();
    for (int e = e0 + tid; e < e1; e += 1024) {
        int d = dst[e];
        int pos = atomicAdd(&lcur[d >> 8], 1);
        unsigned long long p = ((unsigned long long)__float_as_uint(attr[e]) << 32) |
                               ((unsigned long long)(d & 255) << 24) |
                               (unsigned int)src[e];
        tmp[pos] = p;
    }
}

// ------- sort pass B: one block per bucket; exact node placement via LDS cursors.
// Final edata word: [attr_fp32:32 | src:24] (plain src index; consumers shift).
__global__ __launch_bounds__(256) void k_binB(const int* __restrict__ rowptr,
                                              const unsigned long long* __restrict__ tmp,
                                              unsigned long long* __restrict__ edata,
                                              int N) {
    __shared__ int cur[256];
    int b = blockIdx.x;
    int tid = threadIdx.x;
    int nb0 = b << 8;
    int node = nb0 + tid;
    cur[tid] = (node < N) ? rowptr[node] : 0;
    int beg = rowptr[nb0];
    int endnode = nb0 + 256; if (endnode > N) endnode = N;
    int end = rowptr[endnode];
    __syncthreads();
    for (int e = beg + tid; e < end; e += 256) {
        unsigned long long p = tmp[e];
        int dl = (int)((p >> 24) & 255);
        int pos = atomicAdd(&cur[dl], 1);
        edata[pos] = (p & 0xFFFFFFFF00000000ull) | (p & 0xFFFFFFull);
    }
}

// ---- inline BN scale/shift from raw stats ----
__device__ __forceinline__ void bn_coeff(const float* bs, const float* gam,
                                         const float* bet, int c, float inv_n,
                                         float& sc, float& sh) {
    float mean = bs[c] * inv_n;
    float var = bs[64 + c] * inv_n - mean * mean;
    sc = gam[c] * rsqrtf(fmaxf(var, 0.f) + BN_EPS);
    sh = bet[c] - mean * sc;
}

__device__ __forceinline__ float h16lo(unsigned u) {
    return (float)__builtin_bit_cast(_Float16, (unsigned short)(u & 0xFFFFu));
}
__device__ __forceinline__ float h16hi(unsigned u) {
    return (float)__builtin_bit_cast(_Float16, (unsigned short)(u >> 16));
}

// ---- layer-0 gather on raw x (N x 4) ----
__global__ void k_gather4(const int* __restrict__ rowptr,
                          const unsigned long long* __restrict__ edata,
                          const float* __restrict__ x,
                          float* __restrict__ g4, float* __restrict__ degw, int N) {
    int n = blockIdx.x * blockDim.x + threadIdx.x;
    if (n >= N) return;
    int beg = rowptr[n], end = rowptr[n + 1];
    float4 a0 = {0.f, 0.f, 0.f, 0.f}, a1 = {0.f, 0.f, 0.f, 0.f};
    float wsum = 0.f;
    int e = beg;
    for (; e + 1 < end; e += 2) {
        unsigned long long p0 = edata[e], p1 = edata[e + 1];
        float w0 = __uint_as_float((unsigned)(p0 >> 32));
        float w1 = __uint_as_float((unsigned)(p1 >> 32));
        float4 v0 = *(const float4*)((const char*)x + (((unsigned)p0) << 4));
        float4 v1 = *(const float4*)((const char*)x + (((unsigned)p1) << 4));
        a0.x += w0 * v0.x; a0.y += w0 * v0.y; a0.z += w0 * v0.z; a0.w += w0 * v0.w;
        a1.x += w1 * v1.x; a1.y += w1 * v1.y; a1.z += w1 * v1.z; a1.w += w1 * v1.w;
        wsum += w0 + w1;
    }
    if (e < end) {
        unsigned long long p0 = edata[e];
        float w0 = __uint_as_float((unsigned)(p0 >> 32));
        float4 v0 = *(const float4*)((const char*)x + (((unsigned)p0) << 4));
        a0.x += w0 * v0.x; a0.y += w0 * v0.y; a0.z += w0 * v0.z; a0.w += w0 * v0.w;
        wsum += w0;
    }
    float4 r;
    r.x = a0.x + a1.x; r.y = a0.y + a1.y; r.z = a0.z + a1.z; r.w = a0.w + a1.w;
    *(float4*)&g4[(size_t)n * 4] = r;
    degw[n] = wsum;
}

// ---- activation materialization: a16 = fp16(relu(BN(h))), linear [N][64] ----
__global__ __launch_bounds__(256) void k_act(const float* __restrict__ h,
                                             const float* __restrict__ bs,
                                             const float* __restrict__ gam,
                                             const float* __restrict__ bet,
                                             unsigned short* __restrict__ a16,
                                             int N) {
    __shared__ float scS[64], shS[64];
    int tid = threadIdx.x;
    if (tid < 64) {
        float sc, sh;
        bn_coeff(bs, gam, bet, tid, 1.f / (float)N, sc, sh);
        scS[tid] = sc; shS[tid] = sh;
    }
    __syncthreads();
    int c0 = (tid & 15) << 2;
    float4 scv = *(const float4*)&scS[c0];
    float4 shv = *(const float4*)&shS[c0];
    int total = N << 4;  // N*64/4 chunks
    for (int t = blockIdx.x * 256 + tid; t < total; t += gridDim.x * 256) {
        float4 v = *(const float4*)&h[(size_t)t * 4];
        float r0 = fmaxf(fmaf(v.x, scv.x, shv.x), 0.f);
        float r1 = fmaxf(fmaf(v.y, scv.y, shv.y), 0.f);
        float r2 = fmaxf(fmaf(v.z, scv.z, shv.z), 0.f);
        float r3 = fmaxf(fmaf(v.w, scv.w, shv.w), 0.f);
        unsigned q0 = __builtin_bit_cast(unsigned short, (_Float16)r0);
        unsigned q1 = __builtin_bit_cast(unsigned short, (_Float16)r1);
        unsigned q2 = __builtin_bit_cast(unsigned short, (_Float16)r2);
        unsigned q3 = __builtin_bit_cast(unsigned short, (_Float16)r3);
        uint2 o; o.x = q0 | (q1 << 16); o.y = q2 | (q3 << 16);
        *(uint2*)&a16[(size_t)t * 4] = o;
    }
}

// ------- pull gather from pre-activated fp16: S[n] = sum_e w_e * a16[src_e] ----
// One wave per node. Lanes 0-31 handle even edges, 32-63 odd edges; each lane
// carries a channel PAIR (4B uint = 2 fp16). 16 edges/iteration (8 per half,
// 8 independent acc chains per thread) -> 16 outstanding 128B row reads per
// wave to cover random-access latency. Halves combined via shfl_xor(32).
__global__ __launch_bounds__(256) void k_gather16(const int* __restrict__ rowptr,
                                                  const unsigned long long* __restrict__ edata,
                                                  const unsigned short* __restrict__ a16,
                                                  float* __restrict__ S, int N) {
    int wid = (blockIdx.x * blockDim.x + threadIdx.x) >> 6;  // one wave per node
    if (wid >= N) return;
    int lane = threadIdx.x & 63;
    int half = lane >> 5;        // 0: even edges, 1: odd edges
    int cp = lane & 31;          // channel pair index (channels 2cp, 2cp+1)
    unsigned c4 = (unsigned)(cp << 2);  // byte offset of the pair in a 128B row

    int beg = rowptr[wid], end = rowptr[wid + 1];
    int len = end - beg;
    float a0[8] = {0.f, 0.f, 0.f, 0.f, 0.f, 0.f, 0.f, 0.f};
    float a1[8] = {0.f, 0.f, 0.f, 0.f, 0.f, 0.f, 0.f, 0.f};
    int nFull = len & ~15;
    int e0 = beg + half;
    for (int base = 0; base < nFull; base += 16) {
#pragma unroll
        for (int j = 0; j < 8; ++j) {
            unsigned long long p = edata[e0 + base + 2 * j];
            float w = __uint_as_float((unsigned)(p >> 32));
            unsigned off = (((unsigned)p) << 7) | c4;
            unsigned v = *(const unsigned*)((const char*)a16 + off);
            a0[j] = fmaf(w, h16lo(v), a0[j]);
            a1[j] = fmaf(w, h16hi(v), a1[j]);
        }
    }
    if (nFull < len) {
#pragma unroll
        for (int j = 0; j < 8; ++j) {
            int idx = nFull + 2 * j + half;
            unsigned long long p = edata[beg + (idx < len ? idx : len - 1)];
            float w = (idx < len) ? __uint_as_float((unsigned)(p >> 32)) : 0.f;
            unsigned off = (((unsigned)p) << 7) | c4;
            unsigned v = *(const unsigned*)((const char*)a16 + off);
            a0[j] = fmaf(w, h16lo(v), a0[j]);
            a1[j] = fmaf(w, h16hi(v), a1[j]);
        }
    }
    float r0 = ((a0[0] + a0[1]) + (a0[2] + a0[3])) + ((a0[4] + a0[5]) + (a0[6] + a0[7]));
    float r1 = ((a1[0] + a1[1]) + (a1[2] + a1[3])) + ((a1[4] + a1[5]) + (a1[6] + a1[7]));
    r0 += __shfl_xor(r0, 32);
    r1 += __shfl_xor(r1, 32);
    if (half == 0) {
        float2 o; o.x = r0; o.y = r1;
        *(float2*)&S[(size_t)wid * 64 + (cp << 1)] = o;
    }
}

// ---- bf16x3 split helpers ----
__device__ __forceinline__ void split_pack8(const float* v, uint4& H, uint4& L) {
    unsigned hb[8], lb[8];
#pragma unroll
    for (int j = 0; j < 8; ++j) {
        unsigned b = __float_as_uint(v[j]);
        unsigned rb = (b + 0x7FFFu + ((b >> 16) & 1u)) & 0xFFFF0000u;  // RNE bf16
        hb[j] = rb >> 16;
        float lo = v[j] - __uint_as_float(rb);  // exact
        lb[j] = __float_as_uint(lo) >> 16;
    }
    H.x = hb[0] | (hb[1] << 16); H.y = hb[2] | (hb[3] << 16);
    H.z = hb[4] | (hb[5] << 16); H.w = hb[6] | (hb[7] << 16);
    L.x = lb[0] | (lb[1] << 16); L.y = lb[2] | (lb[3] << 16);
    L.z = lb[4] | (lb[5] << 16); L.w = lb[6] | (lb[7] << 16);
}

__device__ __forceinline__ void split_frag(const float* w, bf16x8& hi, bf16x8& lo) {
#pragma unroll
    for (int j = 0; j < 8; ++j) {
        unsigned b = __float_as_uint(w[j]);
        unsigned rb = (b + 0x7FFFu + ((b >> 16) & 1u)) & 0xFFFF0000u;
        hi[j] = (short)(rb >> 16);
        float lof = w[j] - __uint_as_float(rb);
        lo[j] = (short)(__float_as_uint(lof) >> 16);
    }
}

// --- h_raw_out = S@W1 + x@W3 - dw*(x@W2) + dw*b1 + b3 via bf16x3 MFMA.
// PRE=1: x_i operand read from pre-activated fp16 a16 (exact hi/lo split since
// fp16 mantissa (11b) fits in bf16hi+lo (16b)). EMB=1 (layer 0): S/x rows
// reconstructed from g4/x via Wemb during staging.
template <int PRE, int EMB>
__global__ __launch_bounds__(512) void k_update(
    const float* __restrict__ S, float* __restrict__ h,
    const float* __restrict__ degw,
    const float* __restrict__ xin, const float* __restrict__ g4,
    const float* __restrict__ Wemb, const float* __restrict__ bemb,
    const unsigned short* __restrict__ a16,
    const float* __restrict__ W1, const float* __restrict__ b1,
    const float* __restrict__ W2, const float* __restrict__ W3,
    const float* __restrict__ b3,
    float* __restrict__ bnstats, int N) {
    // [Shi | Slo | Hhi | Hlo], 4096 ushorts (8KB) each = 32KB
    __shared__ __align__(16) unsigned short sA[16384];
    __shared__ float dwS[64];

    int tid = threadIdx.x;
    int lane = tid & 63;
    int wv = tid >> 6;            // wave 0..7
    int mg = wv >> 2;             // row-group: rows mg*32 .. mg*32+31
    int nb = wv & 3;              // col-block: cols nb*16 .. nb*16+15
    int c = (nb << 4) | (lane & 15);
    int krow = (lane >> 4) << 3;  // k-offset of this lane's fragment elems

    // ---- B fragments (weights) in registers, one-time ----
    bf16x8 B1h[2], B1l[2], B2h[2], B2l[2], B3h[2], B3l[2];
#pragma unroll
    for (int ks = 0; ks < 2; ++ks) {
        float w1v[8], w2v[8], w3v[8];
        int kb = ks * 32 + krow;
#pragma unroll
        for (int j = 0; j < 8; ++j) {
            int idx = (kb + j) * 64 + c;
            w1v[j] = W1[idx];
            w2v[j] = W2[idx];
            w3v[j] = W3[idx];
        }
        split_frag(w1v, B1h[ks], B1l[ks]);
        split_frag(w2v, B2h[ks], B2l[ks]);
        split_frag(w3v, B3h[ks], B3l[ks]);
    }
    float b1c = b1[c], b3c = b3[c];

    // ---- staging role: thread handles row r, k-chunk kg (8 consecutive k) ----
    int r = tid >> 3;   // 0..63
    int kg = tid & 7;   // 0..7
    int k0 = kg << 3;
    int slot = ((((r >> 4) * 2 + (kg >> 2)) * 64) + ((kg & 3) << 4) + (r & 15)) * 8;

    float we0[8], we1[8], we2[8], we3[8], bev[8];
    if (EMB) {
#pragma unroll
        for (int j = 0; j < 8; ++j) {
            we0[j] = Wemb[k0 + j];
            we1[j] = Wemb[64 + k0 + j];
            we2[j] = Wemb[128 + k0 + j];
            we3[j] = Wemb[192 + k0 + j];
            bev[j] = bemb[k0 + j];
        }
    }

    float bsum = 0.f, bsq = 0.f;
    int numTiles = (N + 63) >> 6;
    for (int tile = blockIdx.x; tile < numTiles; tile += gridDim.x) {
        int n0 = tile << 6;
        __syncthreads();  // protect LDS from previous iteration's readers
        {
            int n = n0 + r;
            float sv[8], hv[8];
            if (n < N) {
                if (EMB) {
                    float4 g = *(const float4*)&g4[(size_t)n * 4];
                    float4 xr = *(const float4*)&xin[(size_t)n * 4];
                    float dw = degw[n];
#pragma unroll
                    for (int j = 0; j < 8; ++j) {
                        sv[j] = fmaf(g.x, we0[j], fmaf(g.y, we1[j],
                                 fmaf(g.z, we2[j], fmaf(g.w, we3[j], dw * bev[j]))));
                        hv[j] = fmaf(xr.x, we0[j], fmaf(xr.y, we1[j],
                                 fmaf(xr.z, we2[j], fmaf(xr.w, we3[j], bev[j]))));
                    }
                } else {
                    const float* Sp = &S[(size_t)n * 64 + k0];
                    float4 s0_ = *(const float4*)Sp;
                    float4 s1_ = *(const float4*)(Sp + 4);
                    sv[0]=s0_.x; sv[1]=s0_.y; sv[2]=s0_.z; sv[3]=s0_.w;
                    sv[4]=s1_.x; sv[5]=s1_.y; sv[6]=s1_.z; sv[7]=s1_.w;
                    uint4 hp = *(const uint4*)((const char*)a16 + (((size_t)n) << 7) + (k0 << 1));
                    hv[0] = h16lo(hp.x); hv[1] = h16hi(hp.x);
                    hv[2] = h16lo(hp.y); hv[3] = h16hi(hp.y);
                    hv[4] = h16lo(hp.z); hv[5] = h16hi(hp.z);
                    hv[6] = h16lo(hp.w); hv[7] = h16hi(hp.w);
                }
            } else {
#pragma unroll
                for (int j = 0; j < 8; ++j) { sv[j] = 0.f; hv[j] = 0.f; }
            }
            uint4 H, L;
            split_pack8(sv, H, L);
            *(uint4*)&sA[slot] = H;
            *(uint4*)&sA[4096 + slot] = L;
            split_pack8(hv, H, L);
            *(uint4*)&sA[8192 + slot] = H;
            *(uint4*)&sA[12288 + slot] = L;
            if (tid < 64) dwS[tid] = (n0 + tid < N) ? degw[n0 + tid] : 0.f;
        }
        __syncthreads();
        // ---- MFMA: acc over K=64 (2 K-steps), 2 M-subtiles per wave ----
        f32x4 accP[2] = {{0.f,0.f,0.f,0.f},{0.f,0.f,0.f,0.f}};
        f32x4 accN[2] = {{0.f,0.f,0.f,0.f},{0.f,0.f,0.f,0.f}};
#pragma unroll
        for (int ks = 0; ks < 2; ++ks) {
#pragma unroll
            for (int mtg = 0; mtg < 2; ++mtg) {
                int mt = mg * 2 + mtg;
                int base = ((mt * 2 + ks) * 64 + lane) * 8;
                bf16x8 aSh = *(const bf16x8*)&sA[base];
                bf16x8 aSl = *(const bf16x8*)&sA[4096 + base];
                bf16x8 aHh = *(const bf16x8*)&sA[8192 + base];
                bf16x8 aHl = *(const bf16x8*)&sA[12288 + base];
                f32x4 p = accP[mtg], q = accN[mtg];
                p = __builtin_amdgcn_mfma_f32_16x16x32_bf16(aSh, B1h[ks], p, 0, 0, 0);
                p = __builtin_amdgcn_mfma_f32_16x16x32_bf16(aSl, B1h[ks], p, 0, 0, 0);
                p = __builtin_amdgcn_mfma_f32_16x16x32_bf16(aSh, B1l[ks], p, 0, 0, 0);
                p = __builtin_amdgcn_mfma_f32_16x16x32_bf16(aHh, B3h[ks], p, 0, 0, 0);
                p = __builtin_amdgcn_mfma_f32_16x16x32_bf16(aHl, B3h[ks], p, 0, 0, 0);
                p = __builtin_amdgcn_mfma_f32_16x16x32_bf16(aHh, B3l[ks], p, 0, 0, 0);
                q = __builtin_amdgcn_mfma_f32_16x16x32_bf16(aHh, B2h[ks], q, 0, 0, 0);
                q = __builtin_amdgcn_mfma_f32_16x16x32_bf16(aHl, B2h[ks], q, 0, 0, 0);
                q = __builtin_amdgcn_mfma_f32_16x16x32_bf16(aHh, B2l[ks], q, 0, 0, 0);
                accP[mtg] = p; accN[mtg] = q;
            }
        }
        // ---- epilogue: C layout col=lane&15, row=(lane>>4)*4+j ----
#pragma unroll
        for (int mtg = 0; mtg < 2; ++mtg) {
            int rowb = mg * 32 + mtg * 16 + ((lane >> 4) << 2);
            float4 dwv = *(const float4*)&dwS[rowb];
            float dwa[4] = {dwv.x, dwv.y, dwv.z, dwv.w};
#pragma unroll
            for (int j = 0; j < 4; ++j) {
                int n = n0 + rowb + j;
                if (n < N) {
                    float val = accP[mtg][j] - dwa[j] * accN[mtg][j] + dwa[j] * b1c + b3c;
                    h[(size_t)n * 64 + c] = val;  // raw (pre-BN)
                    bsum += val;
                    bsq += val * val;
                }
            }
        }
    }
    // ---- BN stats reduction (reuse sA as 1024 floats) ----
    __syncthreads();
    float* red = (float*)sA;
    red[tid] = bsum;
    red[512 + tid] = bsq;
    __syncthreads();
    if (tid < 64) {
        int nb_ = tid >> 4, cl = tid & 15;
        float s = 0.f, qq = 0.f;
#pragma unroll
        for (int i = 0; i < 8; ++i) {
            int t = ((i & 1) << 8) + (nb_ << 6) + ((i >> 1) << 4) + cl;
            s += red[t];
            qq += red[512 + t];
        }
        atomicAdd(&bnstats[tid], s);
        atomicAdd(&bnstats[64 + tid], qq);
    }
}

// ------- pool phase 1: per-graph sums of act(h_raw), sorted-run + atomics -------
#define POOL_TILE 128
__global__ __launch_bounds__(256) void k_poolsum(const float* __restrict__ h,
                                                 const int* __restrict__ batch,
                                                 const float* __restrict__ bsp,
                                                 const float* __restrict__ gamp,
                                                 const float* __restrict__ betp,
                                                 float* __restrict__ gsums, int N) {
    int tid = threadIdx.x;
    int c = tid & 63, q = tid >> 6;
    float sc, sh_;
    bn_coeff(bsp, gamp, betp, c, 1.f / (float)N, sc, sh_);
    int n0 = blockIdx.x * POOL_TILE;
    int nEnd = n0 + POOL_TILE; if (nEnd > N) nEnd = N;
    int g = -1;
    float acc = 0.f;
    for (int n = n0 + q; n < nEnd; n += 4) {
        int b = batch[n];
        if (b != g) {
            if (g >= 0) atomicAdd(&gsums[(size_t)g * 64 + c], acc);
            g = b; acc = 0.f;
        }
        acc += fmaxf(fmaf(h[(size_t)n * 64 + c], sc, sh_), 0.f);
    }
    if (g >= 0) atomicAdd(&gsums[(size_t)g * 64 + c], acc);
}

// ------- pool phase 2: divide by count + MLP head (one 64-thread block / graph) -
__global__ void k_head(const float* __restrict__ gsums, const int* __restrict__ batch,
                       const float* __restrict__ Wl1, const float* __restrict__ bl1,
                       const float* __restrict__ Wl2, const float* __restrict__ bl2,
                       float* __restrict__ out, int N) {
    int g = blockIdx.x;
    int c = threadIdx.x;  // 64 threads
    int lo = 0, hi = N;
    while (lo < hi) { int mid = (lo + hi) >> 1; if (batch[mid] < g) lo = mid + 1; else hi = mid; }
    int start = lo;
    hi = N;
    while (lo < hi) { int mid = (lo + hi) >> 1; if (batch[mid] < g + 1) lo = mid + 1; else hi = mid; }
    int cnt = lo - start;
    float denom = (float)(cnt > 0 ? cnt : 1);
    __shared__ float gS[64], yS[64];
    gS[c] = gsums[(size_t)g * 64 + c] / denom;
    __syncthreads();
    float y = bl1[c];
    for (int k = 0; k < 64; ++k) y += gS[k] * Wl1[k * 64 + c];
    yS[c] = fmaxf(y, 0.f);
    __syncthreads();
    if (c < 3) {
        float o = bl2[c];
        for (int k = 0; k < 64; ++k) o += yS[k] * Wl2[k * 3 + c];
        out[g * 3 + c] = o;
    }
}

extern "C" void kernel_launch(void* const* d_in, const int* in_sizes, int n_in,
                              void* d_out, int out_size, void* d_ws, size_t ws_size,
                              hipStream_t stream) {
    const float* x     = (const float*)d_in[0];
    const int*   eid   = (const int*)d_in[1];
    const float* attr  = (const float*)d_in[2];
    const int*   batch = (const int*)d_in[3];
    const float* Wemb  = (const float*)d_in[4];
    const float* bemb  = (const float*)d_in[5];
    const float* W1    = (const float*)d_in[6];
    const float* b1    = (const float*)d_in[7];
    const float* W2    = (const float*)d_in[8];
    const float* W3    = (const float*)d_in[9];
    const float* b3    = (const float*)d_in[10];
    const float* gamma = (const float*)d_in[11];
    const float* beta  = (const float*)d_in[12];
    const float* Wl1   = (const float*)d_in[13];
    const float* bl1   = (const float*)d_in[14];
    const float* Wl2   = (const float*)d_in[15];
    const float* bl2   = (const float*)d_in[16];

    int N = in_sizes[3];
    int E = in_sizes[2];
    int L = in_sizes[7] / 64;
    int G = out_size / 3;

    const int* src = eid;
    const int* dst = eid + E;

    float* ws      = (float*)d_ws;
    float* h       = ws;                       // N*64
    float* S       = h + (size_t)N * 64;       // N*64
    float* degw    = S + (size_t)N * 64;       // N
    float* g4      = degw + N;                 // N*4
    float* bnstats = g4 + (size_t)N * 4;       // 3*128 (per-layer slots)
    float* gsums   = bnstats + 3 * 128;        // G*64
    int*   deg     = (int*)(gsums + (size_t)G * 64);  // N
    int*   rowptr  = deg + N;                  // N+2
    int*   bsum    = rowptr + (N + 2);         // 1024
    int*   gcur    = bsum + 1024;              // 1024 (bucket cursors)
    unsigned long long* edata = (unsigned long long*)(gcur + 1024);  // E
    unsigned long long* tmp   = edata + E;                           // E
    unsigned short* a16 = (unsigned short*)(((uintptr_t)(tmp + E) + 15) & ~(uintptr_t)15);  // N*64 fp16

    int nScanBlocks = (N + 1023) / 1024;
    int NB = (N + 255) >> 8;  // 256-node buckets (requires N < 2^24, NB <= 1024)

    // ---- CSR build + two-level counting sort of edges by dst ----
    hipMemsetAsync(deg, 0, (size_t)N * sizeof(int), stream);
    hipMemsetAsync(bnstats, 0, 3 * 128 * sizeof(float), stream);
    k_hist<<<(E + 255) / 256, 256, 0, stream>>>(dst, deg, E);
    k_blocksum<<<nScanBlocks, 256, 0, stream>>>(deg, bsum, N);
    k_scanpartials<<<1, 1024, 0, stream>>>(bsum, nScanBlocks);
    k_applyscan<<<nScanBlocks, 256, 0, stream>>>(deg, bsum, rowptr, gcur, N, E);
    k_binA<<<(E + ABLK - 1) / ABLK, 1024, 0, stream>>>(src, dst, attr, gcur, tmp, E, N);
    k_binB<<<NB, 256, 0, stream>>>(rowptr, tmp, edata, N);

    // ---- layers ----
    int gGrid = (N * 64 + 255) / 256;
    for (int l = 0; l < L; ++l) {
        if (l == 0) {
            // layer 0: 4-channel gather on raw x; S0/x0 reconstructed in update
            k_gather4<<<(N + 255) / 256, 256, 0, stream>>>(rowptr, edata, x, g4, degw, N);
            k_update<0, 1><<<1024, 512, 0, stream>>>(S, h, degw, x, g4, Wemb, bemb,
                                                     nullptr,
                                                     W1, b1, W2, W3, b3, bnstats, N);
        } else {
            k_gather16<<<gGrid, 256, 0, stream>>>(rowptr, edata, a16, S, N);
            k_update<1, 0><<<1024, 512, 0, stream>>>(S, h, degw, nullptr, nullptr,
                                                     nullptr, nullptr, a16,
                                                     W1 + (size_t)l * 4096, b1 + (size_t)l * 64,
                                                     W2 + (size_t)l * 4096, W3 + (size_t)l * 4096,
                                                     b3 + (size_t)l * 64,
                                                     bnstats + (size_t)l * 128, N);
        }
        if (l + 1 < L) {
            k_act<<<1024, 256, 0, stream>>>(h, bnstats + (size_t)l * 128,
                                            gamma + (size_t)l * 64, beta + (size_t)l * 64,
                                            a16, N);
        }
    }

    // ---- pool (applies final BN affine + relu lazily) + head ----
    hipMemsetAsync(gsums, 0, (size_t)G * 64 * sizeof(float), stream);
    k_poolsum<<<(N + POOL_TILE - 1) / POOL_TILE, 256, 0, stream>>>(
        h, batch, bnstats + (size_t)(L - 1) * 128, gamma + (size_t)(L - 1) * 64,
        beta + (size_t)(L - 1) * 64, gsums, N);
    k_head<<<G, 64, 0, stream>>>(gsums, batch, Wl1, bl1, Wl2, bl2, (float*)d_out, N);
}

// Round 9
// 391.501 us; speedup vs baseline: 3.5115x; 1.1106x over previous
//
#include <hip/hip_runtime.h>

#define BN_EPS 1e-5f

typedef __attribute__((ext_vector_type(8))) short bf16x8;
typedef __attribute__((ext_vector_type(4))) float f32x4;

#define ABLK 8192

// ---- sort pass A0: bucket counts via LDS histogram (dst>>8), one global
// atomicAdd per (block,bucket) instead of per edge. ----
__global__ __launch_bounds__(1024) void k_countA(const int* __restrict__ dst,
                                                 int* __restrict__ gcnt, int E, int N) {
    __shared__ int hist[1024];
    int tid = threadIdx.x;
    int NB = (N + 255) >> 8;
    int e0 = blockIdx.x * ABLK;
    int e1 = e0 + ABLK; if (e1 > E) e1 = E;
    for (int i = tid; i < NB; i += 1024) hist[i] = 0;
    __syncthreads();
    for (int e = e0 + tid; e < e1; e += 1024) atomicAdd(&hist[dst[e] >> 8], 1);
    __syncthreads();
    for (int b = tid; b < NB; b += 1024) {
        int hc = hist[b];
        if (hc) atomicAdd(&gcnt[b], hc);
    }
}

// ---- sort pass A1: exclusive scan of bucket counts -> bucket bases + cursors --
__global__ __launch_bounds__(1024) void k_scanbuckets(const int* __restrict__ gcnt,
                                                      int* __restrict__ gbase,
                                                      int* __restrict__ gcur,
                                                      int* __restrict__ rowptr,
                                                      int E, int N) {
    __shared__ int t[1024];
    int tid = threadIdx.x;
    int NB = (N + 255) >> 8;
    int v = (tid < NB) ? gcnt[tid] : 0;
    t[tid] = v;
    __syncthreads();
    for (int d = 1; d < 1024; d <<= 1) {
        int u = (tid >= d) ? t[tid - d] : 0;
        __syncthreads();
        t[tid] += u;
        __syncthreads();
    }
    int ex = t[tid] - v;  // exclusive
    if (tid < NB) { gbase[tid] = ex; gcur[tid] = ex; }
    if (tid == 0) { gbase[NB] = E; rowptr[N] = E; }
}

// ------- sort pass A: partition edges into 256-node buckets (requires N < 2^24) -
// Payload: [attr:32 | dst&255:8 | src:24]
__global__ __launch_bounds__(1024) void k_binA(const int* __restrict__ src,
                                               const int* __restrict__ dst,
                                               const float* __restrict__ attr,
                                               int* __restrict__ gcur,
                                               unsigned long long* __restrict__ tmp,
                                               int E, int N) {
    __shared__ int hist[1024];
    __shared__ int lcur[1024];
    int tid = threadIdx.x;
    int NB = (N + 255) >> 8;  // <= 1024 for N <= 262144
    int e0 = blockIdx.x * ABLK;
    int e1 = e0 + ABLK; if (e1 > E) e1 = E;
    for (int i = tid; i < NB; i += 1024) hist[i] = 0;
    __syncthreads();
    for (int e = e0 + tid; e < e1; e += 1024) atomicAdd(&hist[dst[e] >> 8], 1);
    __syncthreads();
    for (int b = tid; b < NB; b += 1024) {
        int hc = hist[b];
        lcur[b] = hc ? atomicAdd(&gcur[b], hc) : 0;
    }
    __syncthreads();
    for (int e = e0 + tid; e < e1; e += 1024) {
        int d = dst[e];
        int pos = atomicAdd(&lcur[d >> 8], 1);
        unsigned long long p = ((unsigned long long)__float_as_uint(attr[e]) << 32) |
                               ((unsigned long long)(d & 255) << 24) |
                               (unsigned int)src[e];
        tmp[pos] = p;
    }
}

// ------- sort pass B: per bucket, LDS histogram of dst&255 -> rowptr (no global
// atomics for degree counting), then exact placement via LDS cursors.
// Final edata word: [attr_fp32:32 | src:24] (plain src index; consumers shift).
__global__ __launch_bounds__(256) void k_binB3(const int* __restrict__ gbase,
                                               const unsigned long long* __restrict__ tmp,
                                               unsigned long long* __restrict__ edata,
                                               int* __restrict__ rowptr, int N) {
    __shared__ int cnt[256];
    __shared__ int scn[256];
    __shared__ int cur[256];
    int b = blockIdx.x;
    int tid = threadIdx.x;
    int nb0 = b << 8;
    int beg = gbase[b], end = gbase[b + 1];
    cnt[tid] = 0;
    __syncthreads();
    for (int e = beg + tid; e < end; e += 256)
        atomicAdd(&cnt[(int)((tmp[e] >> 24) & 255)], 1);
    __syncthreads();
    int v = cnt[tid];
    scn[tid] = v;
    __syncthreads();
    for (int d = 1; d < 256; d <<= 1) {
        int u = (tid >= d) ? scn[tid - d] : 0;
        __syncthreads();
        scn[tid] += u;
        __syncthreads();
    }
    int ex = beg + scn[tid] - v;  // exclusive within bucket + base
    int node = nb0 + tid;
    if (node < N) rowptr[node] = ex;
    cur[tid] = ex;
    __syncthreads();
    for (int e = beg + tid; e < end; e += 256) {
        unsigned long long p = tmp[e];
        int dl = (int)((p >> 24) & 255);
        int pos = atomicAdd(&cur[dl], 1);
        edata[pos] = (p & 0xFFFFFFFF00000000ull) | (p & 0xFFFFFFull);
    }
}

// ---- inline BN scale/shift from raw stats ----
__device__ __forceinline__ void bn_coeff(const float* bs, const float* gam,
                                         const float* bet, int c, float inv_n,
                                         float& sc, float& sh) {
    float mean = bs[c] * inv_n;
    float var = bs[64 + c] * inv_n - mean * mean;
    sc = gam[c] * rsqrtf(fmaxf(var, 0.f) + BN_EPS);
    sh = bet[c] - mean * sc;
}

__device__ __forceinline__ float h16lo(unsigned u) {
    return (float)__builtin_bit_cast(_Float16, (unsigned short)(u & 0xFFFFu));
}
__device__ __forceinline__ float h16hi(unsigned u) {
    return (float)__builtin_bit_cast(_Float16, (unsigned short)(u >> 16));
}

// ---- layer-0 gather on raw x (N x 4) ----
__global__ void k_gather4(const int* __restrict__ rowptr,
                          const unsigned long long* __restrict__ edata,
                          const float* __restrict__ x,
                          float* __restrict__ g4, float* __restrict__ degw, int N) {
    int n = blockIdx.x * blockDim.x + threadIdx.x;
    if (n >= N) return;
    int beg = rowptr[n], end = rowptr[n + 1];
    float4 a0 = {0.f, 0.f, 0.f, 0.f}, a1 = {0.f, 0.f, 0.f, 0.f};
    float wsum = 0.f;
    int e = beg;
    for (; e + 1 < end; e += 2) {
        unsigned long long p0 = edata[e], p1 = edata[e + 1];
        float w0 = __uint_as_float((unsigned)(p0 >> 32));
        float w1 = __uint_as_float((unsigned)(p1 >> 32));
        float4 v0 = *(const float4*)((const char*)x + (((unsigned)p0) << 4));
        float4 v1 = *(const float4*)((const char*)x + (((unsigned)p1) << 4));
        a0.x += w0 * v0.x; a0.y += w0 * v0.y; a0.z += w0 * v0.z; a0.w += w0 * v0.w;
        a1.x += w1 * v1.x; a1.y += w1 * v1.y; a1.z += w1 * v1.z; a1.w += w1 * v1.w;
        wsum += w0 + w1;
    }
    if (e < end) {
        unsigned long long p0 = edata[e];
        float w0 = __uint_as_float((unsigned)(p0 >> 32));
        float4 v0 = *(const float4*)((const char*)x + (((unsigned)p0) << 4));
        a0.x += w0 * v0.x; a0.y += w0 * v0.y; a0.z += w0 * v0.z; a0.w += w0 * v0.w;
        wsum += w0;
    }
    float4 r;
    r.x = a0.x + a1.x; r.y = a0.y + a1.y; r.z = a0.z + a1.z; r.w = a0.w + a1.w;
    *(float4*)&g4[(size_t)n * 4] = r;
    degw[n] = wsum;
}

// ---- activation materialization: a16 = fp16(relu(BN(h))), linear [N][64] ----
__global__ __launch_bounds__(256) void k_act(const float* __restrict__ h,
                                             const float* __restrict__ bs,
                                             const float* __restrict__ gam,
                                             const float* __restrict__ bet,
                                             unsigned short* __restrict__ a16,
                                             int N) {
    __shared__ float scS[64], shS[64];
    int tid = threadIdx.x;
    if (tid < 64) {
        float sc, sh;
        bn_coeff(bs, gam, bet, tid, 1.f / (float)N, sc, sh);
        scS[tid] = sc; shS[tid] = sh;
    }
    __syncthreads();
    int c0 = (tid & 15) << 2;
    float4 scv = *(const float4*)&scS[c0];
    float4 shv = *(const float4*)&shS[c0];
    int total = N << 4;  // N*64/4 chunks
    for (int t = blockIdx.x * 256 + tid; t < total; t += gridDim.x * 256) {
        float4 v = *(const float4*)&h[(size_t)t * 4];
        float r0 = fmaxf(fmaf(v.x, scv.x, shv.x), 0.f);
        float r1 = fmaxf(fmaf(v.y, scv.y, shv.y), 0.f);
        float r2 = fmaxf(fmaf(v.z, scv.z, shv.z), 0.f);
        float r3 = fmaxf(fmaf(v.w, scv.w, shv.w), 0.f);
        unsigned q0 = __builtin_bit_cast(unsigned short, (_Float16)r0);
        unsigned q1 = __builtin_bit_cast(unsigned short, (_Float16)r1);
        unsigned q2 = __builtin_bit_cast(unsigned short, (_Float16)r2);
        unsigned q3 = __builtin_bit_cast(unsigned short, (_Float16)r3);
        uint2 o; o.x = q0 | (q1 << 16); o.y = q2 | (q3 << 16);
        *(uint2*)&a16[(size_t)t * 4] = o;
    }
}

// ------- pull gather from pre-activated fp16: S[n] = sum_e w_e * a16[src_e] ----
// One wave per node. Lanes 0-31 handle even edges, 32-63 odd edges; each lane
// carries a channel PAIR (4B uint = 2 fp16). 16 edges/iteration (8 per half,
// 8 independent acc chains per thread) -> 16 outstanding 128B row reads per
// wave to cover random-access latency. Halves combined via shfl_xor(32).
__global__ __launch_bounds__(256) void k_gather16(const int* __restrict__ rowptr,
                                                  const unsigned long long* __restrict__ edata,
                                                  const unsigned short* __restrict__ a16,
                                                  float* __restrict__ S, int N) {
    int wid = (blockIdx.x * blockDim.x + threadIdx.x) >> 6;  // one wave per node
    if (wid >= N) return;
    int lane = threadIdx.x & 63;
    int half = lane >> 5;        // 0: even edges, 1: odd edges
    int cp = lane & 31;          // channel pair index (channels 2cp, 2cp+1)
    unsigned c4 = (unsigned)(cp << 2);  // byte offset of the pair in a 128B row

    int beg = rowptr[wid], end = rowptr[wid + 1];
    int len = end - beg;
    float a0[8] = {0.f, 0.f, 0.f, 0.f, 0.f, 0.f, 0.f, 0.f};
    float a1[8] = {0.f, 0.f, 0.f, 0.f, 0.f, 0.f, 0.f, 0.f};
    int nFull = len & ~15;
    int e0 = beg + half;
    for (int base = 0; base < nFull; base += 16) {
#pragma unroll
        for (int j = 0; j < 8; ++j) {
            unsigned long long p = edata[e0 + base + 2 * j];
            float w = __uint_as_float((unsigned)(p >> 32));
            unsigned off = (((unsigned)p) << 7) | c4;
            unsigned v = *(const unsigned*)((const char*)a16 + off);
            a0[j] = fmaf(w, h16lo(v), a0[j]);
            a1[j] = fmaf(w, h16hi(v), a1[j]);
        }
    }
    if (nFull < len) {
#pragma unroll
        for (int j = 0; j < 8; ++j) {
            int idx = nFull + 2 * j + half;
            unsigned long long p = edata[beg + (idx < len ? idx : len - 1)];
            float w = (idx < len) ? __uint_as_float((unsigned)(p >> 32)) : 0.f;
            unsigned off = (((unsigned)p) << 7) | c4;
            unsigned v = *(const unsigned*)((const char*)a16 + off);
            a0[j] = fmaf(w, h16lo(v), a0[j]);
            a1[j] = fmaf(w, h16hi(v), a1[j]);
        }
    }
    float r0 = ((a0[0] + a0[1]) + (a0[2] + a0[3])) + ((a0[4] + a0[5]) + (a0[6] + a0[7]));
    float r1 = ((a1[0] + a1[1]) + (a1[2] + a1[3])) + ((a1[4] + a1[5]) + (a1[6] + a1[7]));
    r0 += __shfl_xor(r0, 32);
    r1 += __shfl_xor(r1, 32);
    if (half == 0) {
        float2 o; o.x = r0; o.y = r1;
        *(float2*)&S[(size_t)wid * 64 + (cp << 1)] = o;
    }
}

// ---- bf16x3 split helpers ----
__device__ __forceinline__ void split_pack8(const float* v, uint4& H, uint4& L) {
    unsigned hb[8], lb[8];
#pragma unroll
    for (int j = 0; j < 8; ++j) {
        unsigned b = __float_as_uint(v[j]);
        unsigned rb = (b + 0x7FFFu + ((b >> 16) & 1u)) & 0xFFFF0000u;  // RNE bf16
        hb[j] = rb >> 16;
        float lo = v[j] - __uint_as_float(rb);  // exact
        lb[j] = __float_as_uint(lo) >> 16;
    }
    H.x = hb[0] | (hb[1] << 16); H.y = hb[2] | (hb[3] << 16);
    H.z = hb[4] | (hb[5] << 16); H.w = hb[6] | (hb[7] << 16);
    L.x = lb[0] | (lb[1] << 16); L.y = lb[2] | (lb[3] << 16);
    L.z = lb[4] | (lb[5] << 16); L.w = lb[6] | (lb[7] << 16);
}

__device__ __forceinline__ void split_frag(const float* w, bf16x8& hi, bf16x8& lo) {
#pragma unroll
    for (int j = 0; j < 8; ++j) {
        unsigned b = __float_as_uint(w[j]);
        unsigned rb = (b + 0x7FFFu + ((b >> 16) & 1u)) & 0xFFFF0000u;
        hi[j] = (short)(rb >> 16);
        float lof = w[j] - __uint_as_float(rb);
        lo[j] = (short)(__float_as_uint(lof) >> 16);
    }
}

// --- h_raw_out = S@W1 + x@W3 - dw*(x@W2) + dw*b1 + b3 via bf16x3 MFMA.
// PRE=1: x_i operand read from pre-activated fp16 a16 (exact hi/lo split since
// fp16 mantissa (11b) fits in bf16hi+lo (16b)). EMB=1 (layer 0): S/x rows
// reconstructed from g4/x via Wemb during staging.
template <int PRE, int EMB>
__global__ __launch_bounds__(512) void k_update(
    const float* __restrict__ S, float* __restrict__ h,
    const float* __restrict__ degw,
    const float* __restrict__ xin, const float* __restrict__ g4,
    const float* __restrict__ Wemb, const float* __restrict__ bemb,
    const unsigned short* __restrict__ a16,
    const float* __restrict__ W1, const float* __restrict__ b1,
    const float* __restrict__ W2, const float* __restrict__ W3,
    const float* __restrict__ b3,
    float* __restrict__ bnstats, int N) {
    // [Shi | Slo | Hhi | Hlo], 4096 ushorts (8KB) each = 32KB
    __shared__ __align__(16) unsigned short sA[16384];
    __shared__ float dwS[64];

    int tid = threadIdx.x;
    int lane = tid & 63;
    int wv = tid >> 6;            // wave 0..7
    int mg = wv >> 2;             // row-group: rows mg*32 .. mg*32+31
    int nb = wv & 3;              // col-block: cols nb*16 .. nb*16+15
    int c = (nb << 4) | (lane & 15);
    int krow = (lane >> 4) << 3;  // k-offset of this lane's fragment elems

    // ---- B fragments (weights) in registers, one-time ----
    bf16x8 B1h[2], B1l[2], B2h[2], B2l[2], B3h[2], B3l[2];
#pragma unroll
    for (int ks = 0; ks < 2; ++ks) {
        float w1v[8], w2v[8], w3v[8];
        int kb = ks * 32 + krow;
#pragma unroll
        for (int j = 0; j < 8; ++j) {
            int idx = (kb + j) * 64 + c;
            w1v[j] = W1[idx];
            w2v[j] = W2[idx];
            w3v[j] = W3[idx];
        }
        split_frag(w1v, B1h[ks], B1l[ks]);
        split_frag(w2v, B2h[ks], B2l[ks]);
        split_frag(w3v, B3h[ks], B3l[ks]);
    }
    float b1c = b1[c], b3c = b3[c];

    // ---- staging role: thread handles row r, k-chunk kg (8 consecutive k) ----
    int r = tid >> 3;   // 0..63
    int kg = tid & 7;   // 0..7
    int k0 = kg << 3;
    int slot = ((((r >> 4) * 2 + (kg >> 2)) * 64) + ((kg & 3) << 4) + (r & 15)) * 8;

    float we0[8], we1[8], we2[8], we3[8], bev[8];
    if (EMB) {
#pragma unroll
        for (int j = 0; j < 8; ++j) {
            we0[j] = Wemb[k0 + j];
            we1[j] = Wemb[64 + k0 + j];
            we2[j] = Wemb[128 + k0 + j];
            we3[j] = Wemb[192 + k0 + j];
            bev[j] = bemb[k0 + j];
        }
    }

    float bsum = 0.f, bsq = 0.f;
    int numTiles = (N + 63) >> 6;
    for (int tile = blockIdx.x; tile < numTiles; tile += gridDim.x) {
        int n0 = tile << 6;
        __syncthreads();  // protect LDS from previous iteration's readers
        {
            int n = n0 + r;
            float sv[8], hv[8];
            if (n < N) {
                if (EMB) {
                    float4 g = *(const float4*)&g4[(size_t)n * 4];
                    float4 xr = *(const float4*)&xin[(size_t)n * 4];
                    float dw = degw[n];
#pragma unroll
                    for (int j = 0; j < 8; ++j) {
                        sv[j] = fmaf(g.x, we0[j], fmaf(g.y, we1[j],
                                 fmaf(g.z, we2[j], fmaf(g.w, we3[j], dw * bev[j]))));
                        hv[j] = fmaf(xr.x, we0[j], fmaf(xr.y, we1[j],
                                 fmaf(xr.z, we2[j], fmaf(xr.w, we3[j], bev[j]))));
                    }
                } else {
                    const float* Sp = &S[(size_t)n * 64 + k0];
                    float4 s0_ = *(const float4*)Sp;
                    float4 s1_ = *(const float4*)(Sp + 4);
                    sv[0]=s0_.x; sv[1]=s0_.y; sv[2]=s0_.z; sv[3]=s0_.w;
                    sv[4]=s1_.x; sv[5]=s1_.y; sv[6]=s1_.z; sv[7]=s1_.w;
                    uint4 hp = *(const uint4*)((const char*)a16 + (((size_t)n) << 7) + (k0 << 1));
                    hv[0] = h16lo(hp.x); hv[1] = h16hi(hp.x);
                    hv[2] = h16lo(hp.y); hv[3] = h16hi(hp.y);
                    hv[4] = h16lo(hp.z); hv[5] = h16hi(hp.z);
                    hv[6] = h16lo(hp.w); hv[7] = h16hi(hp.w);
                }
            } else {
#pragma unroll
                for (int j = 0; j < 8; ++j) { sv[j] = 0.f; hv[j] = 0.f; }
            }
            uint4 H, L;
            split_pack8(sv, H, L);
            *(uint4*)&sA[slot] = H;
            *(uint4*)&sA[4096 + slot] = L;
            split_pack8(hv, H, L);
            *(uint4*)&sA[8192 + slot] = H;
            *(uint4*)&sA[12288 + slot] = L;
            if (tid < 64) dwS[tid] = (n0 + tid < N) ? degw[n0 + tid] : 0.f;
        }
        __syncthreads();
        // ---- MFMA: acc over K=64 (2 K-steps), 2 M-subtiles per wave ----
        f32x4 accP[2] = {{0.f,0.f,0.f,0.f},{0.f,0.f,0.f,0.f}};
        f32x4 accN[2] = {{0.f,0.f,0.f,0.f},{0.f,0.f,0.f,0.f}};
#pragma unroll
        for (int ks = 0; ks < 2; ++ks) {
#pragma unroll
            for (int mtg = 0; mtg < 2; ++mtg) {
                int mt = mg * 2 + mtg;
                int base = ((mt * 2 + ks) * 64 + lane) * 8;
                bf16x8 aSh = *(const bf16x8*)&sA[base];
                bf16x8 aSl = *(const bf16x8*)&sA[4096 + base];
                bf16x8 aHh = *(const bf16x8*)&sA[8192 + base];
                bf16x8 aHl = *(const bf16x8*)&sA[12288 + base];
                f32x4 p = accP[mtg], q = accN[mtg];
                p = __builtin_amdgcn_mfma_f32_16x16x32_bf16(aSh, B1h[ks], p, 0, 0, 0);
                p = __builtin_amdgcn_mfma_f32_16x16x32_bf16(aSl, B1h[ks], p, 0, 0, 0);
                p = __builtin_amdgcn_mfma_f32_16x16x32_bf16(aSh, B1l[ks], p, 0, 0, 0);
                p = __builtin_amdgcn_mfma_f32_16x16x32_bf16(aHh, B3h[ks], p, 0, 0, 0);
                p = __builtin_amdgcn_mfma_f32_16x16x32_bf16(aHl, B3h[ks], p, 0, 0, 0);
                p = __builtin_amdgcn_mfma_f32_16x16x32_bf16(aHh, B3l[ks], p, 0, 0, 0);
                q = __builtin_amdgcn_mfma_f32_16x16x32_bf16(aHh, B2h[ks], q, 0, 0, 0);
                q = __builtin_amdgcn_mfma_f32_16x16x32_bf16(aHl, B2h[ks], q, 0, 0, 0);
                q = __builtin_amdgcn_mfma_f32_16x16x32_bf16(aHh, B2l[ks], q, 0, 0, 0);
                accP[mtg] = p; accN[mtg] = q;
            }
        }
        // ---- epilogue: C layout col=lane&15, row=(lane>>4)*4+j ----
#pragma unroll
        for (int mtg = 0; mtg < 2; ++mtg) {
            int rowb = mg * 32 + mtg * 16 + ((lane >> 4) << 2);
            float4 dwv = *(const float4*)&dwS[rowb];
            float dwa[4] = {dwv.x, dwv.y, dwv.z, dwv.w};
#pragma unroll
            for (int j = 0; j < 4; ++j) {
                int n = n0 + rowb + j;
                if (n < N) {
                    float val = accP[mtg][j] - dwa[j] * accN[mtg][j] + dwa[j] * b1c + b3c;
                    h[(size_t)n * 64 + c] = val;  // raw (pre-BN)
                    bsum += val;
                    bsq += val * val;
                }
            }
        }
    }
    // ---- BN stats reduction (reuse sA as 1024 floats) ----
    __syncthreads();
    float* red = (float*)sA;
    red[tid] = bsum;
    red[512 + tid] = bsq;
    __syncthreads();
    if (tid < 64) {
        int nb_ = tid >> 4, cl = tid & 15;
        float s = 0.f, qq = 0.f;
#pragma unroll
        for (int i = 0; i < 8; ++i) {
            int t = ((i & 1) << 8) + (nb_ << 6) + ((i >> 1) << 4) + cl;
            s += red[t];
            qq += red[512 + t];
        }
        atomicAdd(&bnstats[tid], s);
        atomicAdd(&bnstats[64 + tid], qq);
    }
}

// ------- pool phase 1: per-graph sums of act(h_raw), sorted-run + atomics -------
#define POOL_TILE 128
__global__ __launch_bounds__(256) void k_poolsum(const float* __restrict__ h,
                                                 const int* __restrict__ batch,
                                                 const float* __restrict__ bsp,
                                                 const float* __restrict__ gamp,
                                                 const float* __restrict__ betp,
                                                 float* __restrict__ gsums, int N) {
    int tid = threadIdx.x;
    int c = tid & 63, q = tid >> 6;
    float sc, sh_;
    bn_coeff(bsp, gamp, betp, c, 1.f / (float)N, sc, sh_);
    int n0 = blockIdx.x * POOL_TILE;
    int nEnd = n0 + POOL_TILE; if (nEnd > N) nEnd = N;
    int g = -1;
    float acc = 0.f;
    for (int n = n0 + q; n < nEnd; n += 4) {
        int b = batch[n];
        if (b != g) {
            if (g >= 0) atomicAdd(&gsums[(size_t)g * 64 + c], acc);
            g = b; acc = 0.f;
        }
        acc += fmaxf(fmaf(h[(size_t)n * 64 + c], sc, sh_), 0.f);
    }
    if (g >= 0) atomicAdd(&gsums[(size_t)g * 64 + c], acc);
}

// ------- pool phase 2: divide by count + MLP head (one 64-thread block / graph) -
__global__ void k_head(const float* __restrict__ gsums, const int* __restrict__ batch,
                       const float* __restrict__ Wl1, const float* __restrict__ bl1,
                       const float* __restrict__ Wl2, const float* __restrict__ bl2,
                       float* __restrict__ out, int N) {
    int g = blockIdx.x;
    int c = threadIdx.x;  // 64 threads
    int lo = 0, hi = N;
    while (lo < hi) { int mid = (lo + hi) >> 1; if (batch[mid] < g) lo = mid + 1; else hi = mid; }
    int start = lo;
    hi = N;
    while (lo < hi) { int mid = (lo + hi) >> 1; if (batch[mid] < g + 1) lo = mid + 1; else hi = mid; }
    int cnt = lo - start;
    float denom = (float)(cnt > 0 ? cnt : 1);
    __shared__ float gS[64], yS[64];
    gS[c] = gsums[(size_t)g * 64 + c] / denom;
    __syncthreads();
    float y = bl1[c];
    for (int k = 0; k < 64; ++k) y += gS[k] * Wl1[k * 64 + c];
    yS[c] = fmaxf(y, 0.f);
    __syncthreads();
    if (c < 3) {
        float o = bl2[c];
        for (int k = 0; k < 64; ++k) o += yS[k] * Wl2[k * 3 + c];
        out[g * 3 + c] = o;
    }
}

extern "C" void kernel_launch(void* const* d_in, const int* in_sizes, int n_in,
                              void* d_out, int out_size, void* d_ws, size_t ws_size,
                              hipStream_t stream) {
    const float* x     = (const float*)d_in[0];
    const int*   eid   = (const int*)d_in[1];
    const float* attr  = (const float*)d_in[2];
    const int*   batch = (const int*)d_in[3];
    const float* Wemb  = (const float*)d_in[4];
    const float* bemb  = (const float*)d_in[5];
    const float* W1    = (const float*)d_in[6];
    const float* b1    = (const float*)d_in[7];
    const float* W2    = (const float*)d_in[8];
    const float* W3    = (const float*)d_in[9];
    const float* b3    = (const float*)d_in[10];
    const float* gamma = (const float*)d_in[11];
    const float* beta  = (const float*)d_in[12];
    const float* Wl1   = (const float*)d_in[13];
    const float* bl1   = (const float*)d_in[14];
    const float* Wl2   = (const float*)d_in[15];
    const float* bl2   = (const float*)d_in[16];

    int N = in_sizes[3];
    int E = in_sizes[2];
    int L = in_sizes[7] / 64;
    int G = out_size / 3;

    const int* src = eid;
    const int* dst = eid + E;

    float* ws      = (float*)d_ws;
    float* h       = ws;                       // N*64
    float* S       = h + (size_t)N * 64;       // N*64
    float* degw    = S + (size_t)N * 64;       // N
    float* g4      = degw + N;                 // N*4
    float* bnstats = g4 + (size_t)N * 4;       // 3*128 (per-layer slots)
    float* gsums   = bnstats + 3 * 128;        // G*64
    int*   gbase   = (int*)(gsums + (size_t)G * 64);  // NB+1 (reuses old deg slot, N ints)
    int*   rowptr  = gbase + N;                // N+2
    int*   gcnt    = rowptr + (N + 2);         // 1024
    int*   gcur    = gcnt + 1024;              // 1024 (bucket cursors)
    unsigned long long* edata = (unsigned long long*)(gcur + 1024);  // E
    unsigned long long* tmp   = edata + E;                           // E
    unsigned short* a16 = (unsigned short*)(((uintptr_t)(tmp + E) + 15) & ~(uintptr_t)15);  // N*64 fp16

    int NB = (N + 255) >> 8;  // 256-node buckets (requires N < 2^24, NB <= 1024)

    // ---- CSR build + two-level counting sort of edges by dst (no per-edge
    // global atomics: LDS-aggregated bucket counts + per-bucket LDS histograms) --
    hipMemsetAsync(gcnt, 0, 1024 * sizeof(int), stream);
    hipMemsetAsync(bnstats, 0, 3 * 128 * sizeof(float), stream);
    k_countA<<<(E + ABLK - 1) / ABLK, 1024, 0, stream>>>(dst, gcnt, E, N);
    k_scanbuckets<<<1, 1024, 0, stream>>>(gcnt, gbase, gcur, rowptr, E, N);
    k_binA<<<(E + ABLK - 1) / ABLK, 1024, 0, stream>>>(src, dst, attr, gcur, tmp, E, N);
    k_binB3<<<NB, 256, 0, stream>>>(gbase, tmp, edata, rowptr, N);

    // ---- layers ----
    int gGrid = (N * 64 + 255) / 256;
    for (int l = 0; l < L; ++l) {
        if (l == 0) {
            // layer 0: 4-channel gather on raw x; S0/x0 reconstructed in update
            k_gather4<<<(N + 255) / 256, 256, 0, stream>>>(rowptr, edata, x, g4, degw, N);
            k_update<0, 1><<<1024, 512, 0, stream>>>(S, h, degw, x, g4, Wemb, bemb,
                                                     nullptr,
                                                     W1, b1, W2, W3, b3, bnstats, N);
        } else {
            k_gather16<<<gGrid, 256, 0, stream>>>(rowptr, edata, a16, S, N);
            k_update<1, 0><<<1024, 512, 0, stream>>>(S, h, degw, nullptr, nullptr,
                                                     nullptr, nullptr, a16,
                                                     W1 + (size_t)l * 4096, b1 + (size_t)l * 64,
                                                     W2 + (size_t)l * 4096, W3 + (size_t)l * 4096,
                                                     b3 + (size_t)l * 64,
                                                     bnstats + (size_t)l * 128, N);
        }
        if (l + 1 < L) {
            k_act<<<1024, 256, 0, stream>>>(h, bnstats + (size_t)l * 128,
                                            gamma + (size_t)l * 64, beta + (size_t)l * 64,
                                            a16, N);
        }
    }

    // ---- pool (applies final BN affine + relu lazily) + head ----
    hipMemsetAsync(gsums, 0, (size_t)G * 64 * sizeof(float), stream);
    k_poolsum<<<(N + POOL_TILE - 1) / POOL_TILE, 256, 0, stream>>>(
        h, batch, bnstats + (size_t)(L - 1) * 128, gamma + (size_t)(L - 1) * 64,
        beta + (size_t)(L - 1) * 64, gsums, N);
    k_head<<<G, 64, 0, stream>>>(gsums, batch, Wl1, bl1, Wl2, bl2, (float*)d_out, N);
}